// Round 5
// baseline (238.889 us; speedup 1.0000x reference)
//
#include <hip/hip_runtime.h>

// Problem constants (X, Y: (64, 128, 64) fp32)
#define AA   64
#define MM   128
#define DD   64
#define M1   127
#define CSTR 132                 // inc row stride (words); 132%32=4 -> 2-way banks (free)
#define NXY  1024                // XY gram blocks (all 4096 pairs, 4/block)
#define NTRI 544                 // triangle blocks per symmetric gram (a<=b)
#define NBLK (NXY + 2*NTRI)      // 2112
// ws layout: [0,4MB) frag regions {Xhi,Xlo,Yhi,Ylo} each 1MB =
//   path(64) x tile(8) x ks(2) x lane(64) x int4 ; [4MB,..) NBLK partials.
// Requires ws_size >= 4.2 MB.
#define REG_I4 65536             // int4 per 1MB region
#define PART_OFF (4u << 20)

typedef float f32x4 __attribute__((ext_vector_type(4)));
typedef short bf8_t __attribute__((ext_vector_type(8)));

template <int CTRL, int RM>
__device__ __forceinline__ float dpp0(float x) {
    return __int_as_float(
        __builtin_amdgcn_update_dpp(0, __float_as_int(x), CTRL, RM, 0xF, false));
}

__device__ __forceinline__ unsigned bf16_rne(float v) {
    unsigned u = __float_as_uint(v);
    return (u + 0x7FFFu + ((u >> 16) & 1u)) >> 16;
}
__device__ __forceinline__ float bf16_tof(unsigned h) {
    return __uint_as_float(h << 16);
}

// Read->overwrite fence for the 8-row inc buffer: after lgkmcnt(0) every
// prior ds_read has returned data, so the following ds_writes cannot corrupt
// it (covers both HW out-of-order DS completion and compiler reordering;
// sched_barrier stops hipcc hoisting the stores across the inline asm).
__device__ __forceinline__ void lds_fence() {
    asm volatile("s_waitcnt lgkmcnt(0)" ::: "memory");
    __builtin_amdgcn_sched_barrier(0);
}

// ---------------------------------------------------------------------------
// prep: build hi/lo bf16 fragments of dX/dY once, in MFMA fragment order.
// A-frag and B-frag layouts coincide (idx16=lane&15, k=(lane>>4)*8+j), so one
// array serves both operand sides. Row 127 clamped to 126: as A it's the
// never-scanned row 127; as B it's col 127 whose delta is masked at lane 63.
// ---------------------------------------------------------------------------
__global__ __launch_bounds__(256) void prep_frags(const float* __restrict__ X,
                                                  const float* __restrict__ Y,
                                                  int4* __restrict__ frag) {
    const int tid = threadIdx.x, lane = tid & 63, w = tid >> 6;
    const int W    = blockIdx.x * 4 + w;   // 0..1023
    const int inp  = W >> 9;               // 0: X, 1: Y
    const int p    = (W >> 3) & 63;
    const int tile = W & 7;
    const float* S = (inp ? Y : X) + p * (MM * DD);
    int i = tile * 16 + (lane & 15);
    if (i > 126) i = 126;
    const int d0 = (lane >> 4) << 3;

    int4* hi = frag + (inp * 2 + 0) * REG_I4;
    int4* lo = frag + (inp * 2 + 1) * REG_I4;
    const int base = p * 1024 + tile * 128 + lane;

    #pragma unroll
    for (int ks = 0; ks < 2; ++ks) {
        const float* r0 = S + i * DD + ks * 32 + d0;
        const float* r1 = r0 + DD;
        float4 a0 = *(const float4*)r0;
        float4 a1 = *(const float4*)(r0 + 4);
        float4 c0 = *(const float4*)r1;
        float4 c1 = *(const float4*)(r1 + 4);
        float v[8] = {c0.x - a0.x, c0.y - a0.y, c0.z - a0.z, c0.w - a0.w,
                      c1.x - a1.x, c1.y - a1.y, c1.z - a1.z, c1.w - a1.w};
        unsigned hs[8], ls[8];
        #pragma unroll
        for (int e = 0; e < 8; ++e) {
            hs[e] = bf16_rne(v[e]);
            ls[e] = bf16_rne(v[e] - bf16_tof(hs[e]));
        }
        int4 h, l;
        h.x = hs[0] | (hs[1] << 16); h.y = hs[2] | (hs[3] << 16);
        h.z = hs[4] | (hs[5] << 16); h.w = hs[6] | (hs[7] << 16);
        l.x = ls[0] | (ls[1] << 16); l.y = ls[2] | (ls[3] << 16);
        l.z = ls[4] | (ls[5] << 16); l.w = ls[6] | (ls[7] << 16);
        hi[base + ks * 64] = h;
        lo[base + ks * 64] = l;
    }
}

// ---------------------------------------------------------------------------
// Scan helpers. Recurrence (algebraically identical to the R4/R5-verified
// row update, derived via S(l)-S(l-1)=e0+e1 and k0(l+1)=1+S(l)):
//   k0 = 1 + sr1(S_prev)          (K_prev[2l])
//   k1 = 1 + S_prev - e1p         (K_prev[2l+1])
//   e0 = e0p + k0*s0 ; e1 = e1p + k1*s1 (s1 masked 0 at lane 63)
//   S  = incl_scan64(e0 + e1)
// Carrying e0p/e1p avoids the cancellation-prone k1-k0 subtract.
// Final K[127][127] = 1 + S_prev - e1p at lane 63 after the last row.
// ---------------------------------------------------------------------------
template <int ROWS>
__device__ __forceinline__ void load_sv(const float* incW, int c2l, float2* sv) {
    #pragma unroll
    for (int r = 0; r < ROWS; ++r)
        sv[r] = *(const float2*)(incW + r * CSTR + c2l);
}

template <int ROWS>
__device__ __forceinline__ void chain_sv(const float2* sv, int lane,
                                         float& Sv, float& e0p, float& e1p) {
    #pragma unroll
    for (int r = 0; r < ROWS; ++r) {
        float s0 = sv[r].x;
        float s1 = (lane < 63) ? sv[r].y : 0.0f;
        float Sp  = dpp0<0x138, 0xF>(Sv);            // S_prev(l-1), 0 at lane0
        float k0v = 1.0f + Sp;
        float k1v = 1.0f + Sv - e1p;
        float e0  = fmaf(k0v, s0, e0p);
        float e1  = fmaf(k1v, s1, e1p);
        float S   = e0 + e1;
        S += dpp0<0x111, 0xF>(S);                    // row_shr:1
        S += dpp0<0x112, 0xF>(S);                    // row_shr:2
        S += dpp0<0x114, 0xF>(S);                    // row_shr:4
        S += dpp0<0x118, 0xF>(S);                    // row_shr:8
        S += dpp0<0x142, 0xA>(S);                    // row_bcast:15
        S += dpp0<0x143, 0xC>(S);                    // row_bcast:31
        Sv = S; e0p = e0; e1p = e1;
    }
}

// ---------------------------------------------------------------------------
// PDE kernel. gid < 1024: XY gram (all pairs). Else triangle blocks for
// XX / YY (a<=b only; weight 2 off-diag, 1 diag, 0 ragged).
// v4 structure: 8-row inc buffer stored in two predicated halves. Each
// overwrite of the buffer is preceded by lds_fence() (lgkmcnt(0) drain), so
// all prior reads have returned -- v3 omitted this and corrupted the scan.
// Halved incS (33.8->16.9 KB) cuts LDS 67->49.9 KB, targeting 3 blocks/CU
// (R3 counters: 44% VALU + 23% MFMA + 0 conflicts = issue starvation at 2).
// ---------------------------------------------------------------------------
__global__ __launch_bounds__(256, 3)
void sig_pde(const int4* __restrict__ frag, float* __restrict__ partials) {
    const int tid = threadIdx.x, lane = tid & 63, w = tid >> 6;
    const int gid = blockIdx.x;

    int a, b, ain, bin;
    float wgt;
    if (gid < NXY) {
        b = gid >> 4; a = ((gid & 15) << 2) | w;
        ain = 0; bin = 1;
        wgt = -2.0f / 4096.0f;
    } else {
        int t = gid - NXY;
        int inp = 0;
        if (t >= NTRI) { t -= NTRI; inp = 1; }
        int q = (int)((__builtin_sqrtf((float)(2 * t + 1)) - 1.0f) * 0.5f);
        while (2 * (q + 1) * (q + 2) <= t) ++q;
        while (q > 0 && 2 * q * (q + 1) > t) --q;
        int r  = t - 2 * q * (q + 1);
        int i  = r / (q + 1);
        int ag = r - i * (q + 1);
        b = 4 * q + i; a = 4 * ag + w;
        ain = bin = inp;
        wgt = (a < b) ? (2.0f / 4096.0f) : ((a == b) ? (1.0f / 4096.0f) : 0.0f);
    }

    __shared__ int4  Bh[1024], Bl[1024];     // 32 KB B fragments (hi/lo)
    __shared__ float incS[4][8 * CSTR];      // 16.9 KB per-wave 8-row buffers
    __shared__ float red4[4];

    // --- stage this block's B fragment set (flat 32 KB copy, no converts) --
    {
        const int4* Bhg = frag + (bin * 2 + 0) * REG_I4 + b * 1024;
        const int4* Blg = frag + (bin * 2 + 1) * REG_I4 + b * 1024;
        #pragma unroll
        for (int c = 0; c < 4; ++c) {
            int idx = c * 256 + tid;
            Bh[idx] = Bhg[idx];
            Bl[idx] = Blg[idx];
        }
    }
    __syncthreads();

    const int4* Ahg = frag + (ain * 2 + 0) * REG_I4 + a * 1024;
    const int4* Alg = frag + (ain * 2 + 1) * REG_I4 + a * 1024;

    int4 Ah[2][2], Al[2][2];                 // A frags for the 2 strips of a pass
    f32x4 acc[2][8];
    float Sv = 0.0f, e0p = 0.0f, e1p = 0.0f; // scan state (K_prev row, implicit)

    float* incW = &incS[w][0];
    const int c2l = lane << 1;
    const int r0w = (lane >> 4) << 2, c0w = lane & 15;

// 96 MFMA on the current pass's 2 strips; each B fragment read once.
#define MFMA_PASS() do {                                                        \
    _Pragma("unroll")                                                           \
    for (int st_ = 0; st_ < 2; ++st_)                                           \
        _Pragma("unroll")                                                       \
        for (int t_ = 0; t_ < 8; ++t_) acc[st_][t_] = (f32x4){0.f,0.f,0.f,0.f}; \
    _Pragma("unroll")                                                           \
    for (int s_ = 0; s_ < 2; ++s_) {                                            \
        bf8_t ah0 = __builtin_bit_cast(bf8_t, Ah[0][s_]);                       \
        bf8_t al0 = __builtin_bit_cast(bf8_t, Al[0][s_]);                       \
        bf8_t ah1 = __builtin_bit_cast(bf8_t, Ah[1][s_]);                       \
        bf8_t al1 = __builtin_bit_cast(bf8_t, Al[1][s_]);                       \
        _Pragma("unroll")                                                       \
        for (int t_ = 0; t_ < 8; ++t_) {                                        \
            int fb = (t_ * 2 + s_) * 64 + lane;                                 \
            bf8_t bh = *(const bf8_t*)&Bh[fb];                                  \
            bf8_t bl = *(const bf8_t*)&Bl[fb];                                  \
            acc[0][t_] = __builtin_amdgcn_mfma_f32_16x16x32_bf16(ah0, bh, acc[0][t_], 0, 0, 0); \
            acc[1][t_] = __builtin_amdgcn_mfma_f32_16x16x32_bf16(ah1, bh, acc[1][t_], 0, 0, 0); \
            acc[0][t_] = __builtin_amdgcn_mfma_f32_16x16x32_bf16(ah0, bl, acc[0][t_], 0, 0, 0); \
            acc[1][t_] = __builtin_amdgcn_mfma_f32_16x16x32_bf16(ah1, bl, acc[1][t_], 0, 0, 0); \
            acc[0][t_] = __builtin_amdgcn_mfma_f32_16x16x32_bf16(al0, bh, acc[0][t_], 0, 0, 0); \
            acc[1][t_] = __builtin_amdgcn_mfma_f32_16x16x32_bf16(al1, bh, acc[1][t_], 0, 0, 0); \
        }                                                                       \
    }                                                                           \
} while (0)

// Half-strip store: half 0 -> strip rows 0..7 (lanes r0w<8), half 1 ->
// strip rows 8..15 (lanes r0w>=8), both landing on buffer rows 0..7.
// MUST be preceded by lds_fence() (prior reads of the buffer returned).
#define STORE_H(st, half) do {                                 \
    if ((r0w & 8) == ((half) << 3)) {                          \
        float* pb = incW + (r0w & 7) * CSTR + c0w;             \
        _Pragma("unroll")                                      \
        for (int t_ = 0; t_ < 8; ++t_) {                       \
            float* q = pb + (t_ << 4);                         \
            q[0]        = acc[st][t_][0];                      \
            q[CSTR]     = acc[st][t_][1];                      \
            q[2 * CSTR] = acc[st][t_][2];                      \
            q[3 * CSTR] = acc[st][t_][3];                      \
        }                                                      \
    }                                                          \
} while (0)

#define LOAD_A(poff) do {                                      \
    int off = (poff) + lane;                                   \
    Ah[0][0] = Ahg[off];       Ah[0][1] = Ahg[off + 64];       \
    Al[0][0] = Alg[off];       Al[0][1] = Alg[off + 64];       \
    Ah[1][0] = Ahg[off + 128]; Ah[1][1] = Ahg[off + 192];      \
    Al[1][0] = Alg[off + 128]; Al[1][1] = Alg[off + 192];      \
} while (0)

    // prologue: fragments + MFMAs for pass 0 (strips 0,1)
    LOAD_A(0);
    MFMA_PASS();

    for (int pass = 0; pass < 4; ++pass) {
        if (pass < 3) LOAD_A((pass + 1) * 256);  // A regs consumed by prev MFMA_PASS

        // ---- strip 2*pass (acc[0]) : two fenced 8-row phases ------------
        {
            float2 svA[8], svB[8];
            lds_fence(); STORE_H(0, 0);
            load_sv<8>(incW, c2l, svA);
            lds_fence(); STORE_H(0, 1);
            load_sv<8>(incW, c2l, svB);
            chain_sv<8>(svA, lane, Sv, e0p, e1p);
            chain_sv<8>(svB, lane, Sv, e0p, e1p);
        }

        // ---- strip 2*pass+1 (acc[1]) ------------------------------------
        if (pass < 3) {
            float2 svA[8], svB[8];
            lds_fence(); STORE_H(1, 0);
            load_sv<8>(incW, c2l, svA);
            lds_fence(); STORE_H(1, 1);
            load_sv<8>(incW, c2l, svB);
            MFMA_PASS();                         // next pass's accs; hides
            chain_sv<8>(svA, lane, Sv, e0p, e1p);//   under these two chains
            chain_sv<8>(svB, lane, Sv, e0p, e1p);
        } else {
            float2 svA[8], svB[7];               // last strip: 8 + 7 rows
            lds_fence(); STORE_H(1, 0);
            load_sv<8>(incW, c2l, svA);
            lds_fence(); STORE_H(1, 1);
            load_sv<7>(incW, c2l, svB);
            chain_sv<8>(svA, lane, Sv, e0p, e1p);
            chain_sv<7>(svB, lane, Sv, e0p, e1p);
        }
    }

    if (lane == 63) red4[w] = wgt * (1.0f + Sv - e1p);  // weighted K[127][127]
    __syncthreads();
    if (tid == 0)
        partials[gid] = red4[0] + red4[1] + red4[2] + red4[3];

#undef MFMA_PASS
#undef STORE_H
#undef LOAD_A
}

// ---------------------------------------------------------------------------
// final: out[0] = sum(partials) + mean((X0-Y0)^2). Folds the msq term with
// the 1/4096 mean weight so one reduction suffices.
// ---------------------------------------------------------------------------
__global__ void final_sum(const float* __restrict__ X, const float* __restrict__ Y,
                          const float* __restrict__ partials, float* __restrict__ out) {
    __shared__ float red[4];
    int tid = threadIdx.x;                   // 256 threads
    float acc = 0.f;
    for (int e = tid; e < NBLK; e += 256) acc += partials[e];
    for (int e = tid; e < AA * DD; e += 256) {
        int aa = e >> 6, d = e & 63;
        float df = X[aa * (MM * DD) + d] - Y[aa * (MM * DD) + d];
        acc = fmaf(df * df, 1.0f / 4096.0f, acc);
    }
    #pragma unroll
    for (int off = 32; off > 0; off >>= 1) acc += __shfl_down(acc, off);
    if ((tid & 63) == 0) red[tid >> 6] = acc;
    __syncthreads();
    if (tid == 0) out[0] = red[0] + red[1] + red[2] + red[3];
}

extern "C" void kernel_launch(void* const* d_in, const int* in_sizes, int n_in,
                              void* d_out, int out_size, void* d_ws, size_t ws_size,
                              hipStream_t stream) {
    const float* X = (const float*)d_in[0];
    const float* Y = (const float*)d_in[1];
    float* out = (float*)d_out;
    int4*  frag = (int4*)d_ws;
    float* partials = (float*)((char*)d_ws + PART_OFF);

    hipLaunchKernelGGL(prep_frags, dim3(256), dim3(256), 0, stream, X, Y, frag);
    hipLaunchKernelGGL(sig_pde, dim3(NBLK), dim3(256), 0, stream, frag, partials);
    hipLaunchKernelGGL(final_sum, dim3(1), dim3(256), 0, stream, X, Y, partials, out);
}

// Round 6
// 142.916 us; speedup vs baseline: 1.6715x; 1.6715x over previous
//
#include <hip/hip_runtime.h>

// Problem constants (X, Y: (64, 128, 64) fp32)
#define AA   64
#define MM   128
#define DD   64
#define M1   127
#define CSTR 132                 // inc row stride (words); 132%32=4 -> 2-way banks (free)
#define NXY  1024                // XY gram blocks (all 4096 pairs, 4/block)
#define NTRI 544                 // triangle blocks per symmetric gram (a<=b)
#define NBLK (NXY + 2*NTRI)      // 2112
// ws layout: [0,4MB) frag regions {Xhi,Xlo,Yhi,Ylo} each 1MB =
//   path(64) x tile(8) x ks(2) x lane(64) x int4 ; [4MB,..) NBLK partials.
// Requires ws_size >= 4.2 MB.
#define REG_I4 65536             // int4 per 1MB region
#define PART_OFF (4u << 20)

typedef float f32x4 __attribute__((ext_vector_type(4)));
typedef short bf8_t __attribute__((ext_vector_type(8)));

template <int CTRL, int RM>
__device__ __forceinline__ float dpp0(float x) {
    return __int_as_float(
        __builtin_amdgcn_update_dpp(0, __float_as_int(x), CTRL, RM, 0xF, false));
}

__device__ __forceinline__ unsigned bf16_rne(float v) {
    unsigned u = __float_as_uint(v);
    return (u + 0x7FFFu + ((u >> 16) & 1u)) >> 16;
}
__device__ __forceinline__ float bf16_tof(unsigned h) {
    return __uint_as_float(h << 16);
}

// Read->overwrite fence for the 8-row inc buffer: after lgkmcnt(0) every
// prior ds_read has returned data, so the following ds_writes cannot corrupt
// it (covers both HW out-of-order DS completion and compiler reordering;
// sched_barrier stops hipcc hoisting the stores across the inline asm).
// Correctness of this scheme verified in R5 (absmax 0).
__device__ __forceinline__ void lds_fence() {
    asm volatile("s_waitcnt lgkmcnt(0)" ::: "memory");
    __builtin_amdgcn_sched_barrier(0);
}

// ---------------------------------------------------------------------------
// prep: build hi/lo bf16 fragments of dX/dY once, in MFMA fragment order.
// A-frag and B-frag layouts coincide (idx16=lane&15, k=(lane>>4)*8+j), so one
// array serves both operand sides. Row 127 clamped to 126: as A it's the
// never-scanned row 127; as B it's col 127 whose delta is masked at lane 63.
// ---------------------------------------------------------------------------
__global__ __launch_bounds__(256) void prep_frags(const float* __restrict__ X,
                                                  const float* __restrict__ Y,
                                                  int4* __restrict__ frag) {
    const int tid = threadIdx.x, lane = tid & 63, w = tid >> 6;
    const int W    = blockIdx.x * 4 + w;   // 0..1023
    const int inp  = W >> 9;               // 0: X, 1: Y
    const int p    = (W >> 3) & 63;
    const int tile = W & 7;
    const float* S = (inp ? Y : X) + p * (MM * DD);
    int i = tile * 16 + (lane & 15);
    if (i > 126) i = 126;
    const int d0 = (lane >> 4) << 3;

    int4* hi = frag + (inp * 2 + 0) * REG_I4;
    int4* lo = frag + (inp * 2 + 1) * REG_I4;
    const int base = p * 1024 + tile * 128 + lane;

    #pragma unroll
    for (int ks = 0; ks < 2; ++ks) {
        const float* r0 = S + i * DD + ks * 32 + d0;
        const float* r1 = r0 + DD;
        float4 a0 = *(const float4*)r0;
        float4 a1 = *(const float4*)(r0 + 4);
        float4 c0 = *(const float4*)r1;
        float4 c1 = *(const float4*)(r1 + 4);
        float v[8] = {c0.x - a0.x, c0.y - a0.y, c0.z - a0.z, c0.w - a0.w,
                      c1.x - a1.x, c1.y - a1.y, c1.z - a1.z, c1.w - a1.w};
        unsigned hs[8], ls[8];
        #pragma unroll
        for (int e = 0; e < 8; ++e) {
            hs[e] = bf16_rne(v[e]);
            ls[e] = bf16_rne(v[e] - bf16_tof(hs[e]));
        }
        int4 h, l;
        h.x = hs[0] | (hs[1] << 16); h.y = hs[2] | (hs[3] << 16);
        h.z = hs[4] | (hs[5] << 16); h.w = hs[6] | (hs[7] << 16);
        l.x = ls[0] | (ls[1] << 16); l.y = ls[2] | (ls[3] << 16);
        l.z = ls[4] | (ls[5] << 16); l.w = ls[6] | (ls[7] << 16);
        hi[base + ks * 64] = h;
        lo[base + ks * 64] = l;
    }
}

// ---------------------------------------------------------------------------
// Scan helpers. Recurrence (R4/R5-verified):
//   k0 = 1 + sr1(S_prev); k1 = 1 + S_prev - e1p
//   e0 = e0p + k0*s0 ; e1 = e1p + k1*s1 (s1 masked 0 at lane 63)
//   S  = incl_scan64(e0 + e1)
// Final K[127][127] = 1 + S_prev - e1p at lane 63 after the last row.
// ---------------------------------------------------------------------------
template <int ROWS>
__device__ __forceinline__ void load_sv(const float* incW, int c2l, float2* sv) {
    #pragma unroll
    for (int r = 0; r < ROWS; ++r)
        sv[r] = *(const float2*)(incW + r * CSTR + c2l);
}

template <int ROWS>
__device__ __forceinline__ void chain_sv(const float2* sv, int lane,
                                         float& Sv, float& e0p, float& e1p) {
    #pragma unroll
    for (int r = 0; r < ROWS; ++r) {
        float s0 = sv[r].x;
        float s1 = (lane < 63) ? sv[r].y : 0.0f;
        float Sp  = dpp0<0x138, 0xF>(Sv);            // S_prev(l-1), 0 at lane0
        float k0v = 1.0f + Sp;
        float k1v = 1.0f + Sv - e1p;
        float e0  = fmaf(k0v, s0, e0p);
        float e1  = fmaf(k1v, s1, e1p);
        float S   = e0 + e1;
        S += dpp0<0x111, 0xF>(S);                    // row_shr:1
        S += dpp0<0x112, 0xF>(S);                    // row_shr:2
        S += dpp0<0x114, 0xF>(S);                    // row_shr:4
        S += dpp0<0x118, 0xF>(S);                    // row_shr:8
        S += dpp0<0x142, 0xA>(S);                    // row_bcast:15
        S += dpp0<0x143, 0xC>(S);                    // row_bcast:31
        Sv = S; e0p = e0; e1p = e1;
    }
}

// ---------------------------------------------------------------------------
// PDE kernel. gid < 1024: XY gram (all pairs). Else triangle blocks for
// XX / YY (a<=b only; weight 2 off-diag, 1 diag, 0 ragged).
// v5: single-strip acc[8] (32 AGPR, not 64 -- v4's (256,3) cap spilled sv to
// scratch: WRITE_SIZE 500 MB, HBM-bound). Peak live now ~120 unified regs,
// under the 170 cap of 3 waves/SIMD. LDS 49 KB (8-row fenced inc buffer,
// R5-verified) -> 3 blocks/CU. Next strip's MFMAs issue between the two
// 8-row chains so matrix pipe + B-reads hide under pure-VALU scan.
// ---------------------------------------------------------------------------
__global__ __launch_bounds__(256, 3)
void sig_pde(const int4* __restrict__ frag, float* __restrict__ partials) {
    const int tid = threadIdx.x, lane = tid & 63, w = tid >> 6;
    const int gid = blockIdx.x;

    int a, b, ain, bin;
    float wgt;
    if (gid < NXY) {
        b = gid >> 4; a = ((gid & 15) << 2) | w;
        ain = 0; bin = 1;
        wgt = -2.0f / 4096.0f;
    } else {
        int t = gid - NXY;
        int inp = 0;
        if (t >= NTRI) { t -= NTRI; inp = 1; }
        int q = (int)((__builtin_sqrtf((float)(2 * t + 1)) - 1.0f) * 0.5f);
        while (2 * (q + 1) * (q + 2) <= t) ++q;
        while (q > 0 && 2 * q * (q + 1) > t) --q;
        int r  = t - 2 * q * (q + 1);
        int i  = r / (q + 1);
        int ag = r - i * (q + 1);
        b = 4 * q + i; a = 4 * ag + w;
        ain = bin = inp;
        wgt = (a < b) ? (2.0f / 4096.0f) : ((a == b) ? (1.0f / 4096.0f) : 0.0f);
    }

    __shared__ int4  Bh[1024], Bl[1024];     // 32 KB B fragments (hi/lo)
    __shared__ float incS[4][8 * CSTR];      // 16.9 KB per-wave 8-row buffers
    __shared__ float red4[4];

    // --- stage this block's B fragment set (flat 32 KB copy, no converts) --
    {
        const int4* Bhg = frag + (bin * 2 + 0) * REG_I4 + b * 1024;
        const int4* Blg = frag + (bin * 2 + 1) * REG_I4 + b * 1024;
        #pragma unroll
        for (int c = 0; c < 4; ++c) {
            int idx = c * 256 + tid;
            Bh[idx] = Bhg[idx];
            Bl[idx] = Blg[idx];
        }
    }
    __syncthreads();

    const int4* Ahg = frag + (ain * 2 + 0) * REG_I4 + a * 1024;
    const int4* Alg = frag + (ain * 2 + 1) * REG_I4 + a * 1024;

    int4 Ah[2], Al[2], Ahn[2], Aln[2];       // current + prefetched A frags
    f32x4 acc[8];
    float Sv = 0.0f, e0p = 0.0f, e1p = 0.0f; // scan state (K_prev row, implicit)

    float* incW = &incS[w][0];
    const int c2l = lane << 1;
    const int r0w = (lane >> 4) << 2, c0w = lane & 15;

// 48 MFMA on the current strip (hi*hi + hi*lo + lo*hi), acc[8] = 32 AGPR.
#define MFMA_STRIP() do {                                                       \
    _Pragma("unroll")                                                           \
    for (int t_ = 0; t_ < 8; ++t_) acc[t_] = (f32x4){0.f, 0.f, 0.f, 0.f};       \
    _Pragma("unroll")                                                           \
    for (int s_ = 0; s_ < 2; ++s_) {                                            \
        bf8_t ah = __builtin_bit_cast(bf8_t, Ah[s_]);                           \
        bf8_t al = __builtin_bit_cast(bf8_t, Al[s_]);                           \
        _Pragma("unroll")                                                       \
        for (int t_ = 0; t_ < 8; ++t_) {                                        \
            int fb = (t_ * 2 + s_) * 64 + lane;                                 \
            bf8_t bh = *(const bf8_t*)&Bh[fb];                                  \
            bf8_t bl = *(const bf8_t*)&Bl[fb];                                  \
            acc[t_] = __builtin_amdgcn_mfma_f32_16x16x32_bf16(ah, bh, acc[t_], 0, 0, 0); \
            acc[t_] = __builtin_amdgcn_mfma_f32_16x16x32_bf16(ah, bl, acc[t_], 0, 0, 0); \
            acc[t_] = __builtin_amdgcn_mfma_f32_16x16x32_bf16(al, bh, acc[t_], 0, 0, 0); \
        }                                                                       \
    }                                                                           \
} while (0)

// Half-strip store: half 0 -> strip rows 0..7 (lanes r0w<8), half 1 ->
// strip rows 8..15 (lanes r0w>=8), both landing on buffer rows 0..7.
// MUST be preceded by lds_fence() (prior reads of the buffer returned).
#define STORE_H(half) do {                                     \
    if ((r0w & 8) == ((half) << 3)) {                          \
        float* pb = incW + (r0w & 7) * CSTR + c0w;             \
        _Pragma("unroll")                                      \
        for (int t_ = 0; t_ < 8; ++t_) {                       \
            float* q = pb + (t_ << 4);                         \
            q[0]        = acc[t_][0];                          \
            q[CSTR]     = acc[t_][1];                          \
            q[2 * CSTR] = acc[t_][2];                          \
            q[3 * CSTR] = acc[t_][3];                          \
        }                                                      \
    }                                                          \
} while (0)

#define LOAD_A_N(poff) do {                                    \
    int off = (poff) + lane;                                   \
    Ahn[0] = Ahg[off]; Ahn[1] = Ahg[off + 64];                 \
    Aln[0] = Alg[off]; Aln[1] = Alg[off + 64];                 \
} while (0)

    // prologue: strip 0 fragments + MFMAs
    Ah[0] = Ahg[lane]; Ah[1] = Ahg[64 + lane];
    Al[0] = Alg[lane]; Al[1] = Alg[64 + lane];
    MFMA_STRIP();                            // acc = inc strip 0

    for (int s = 0; s < 8; ++s) {
        if (s < 7) LOAD_A_N((s + 1) * 128);  // prefetch next strip's A frags

        // transpose acc -> regs via fenced 8-row buffer (R5-verified scheme)
        float2 svA[8];
        lds_fence(); STORE_H(0);
        load_sv<8>(incW, c2l, svA);
        lds_fence(); STORE_H(1);

        if (s < 7) {
            float2 svB[8];
            load_sv<8>(incW, c2l, svB);
            chain_sv<8>(svA, lane, Sv, e0p, e1p);
            Ah[0] = Ahn[0]; Ah[1] = Ahn[1];  // consume prefetch
            Al[0] = Aln[0]; Al[1] = Aln[1];
            MFMA_STRIP();                    // next strip; hides under chains
            chain_sv<8>(svB, lane, Sv, e0p, e1p);
        } else {
            float2 svB[7];                   // last strip: 8 + 7 rows
            load_sv<7>(incW, c2l, svB);
            chain_sv<8>(svA, lane, Sv, e0p, e1p);
            chain_sv<7>(svB, lane, Sv, e0p, e1p);
        }
    }

    if (lane == 63) red4[w] = wgt * (1.0f + Sv - e1p);  // weighted K[127][127]
    __syncthreads();
    if (tid == 0)
        partials[gid] = red4[0] + red4[1] + red4[2] + red4[3];

#undef MFMA_STRIP
#undef STORE_H
#undef LOAD_A_N
}

// ---------------------------------------------------------------------------
// final: out[0] = sum(partials) + mean((X0-Y0)^2). Folds the msq term with
// the 1/4096 mean weight so one reduction suffices.
// ---------------------------------------------------------------------------
__global__ void final_sum(const float* __restrict__ X, const float* __restrict__ Y,
                          const float* __restrict__ partials, float* __restrict__ out) {
    __shared__ float red[4];
    int tid = threadIdx.x;                   // 256 threads
    float acc = 0.f;
    for (int e = tid; e < NBLK; e += 256) acc += partials[e];
    for (int e = tid; e < AA * DD; e += 256) {
        int aa = e >> 6, d = e & 63;
        float df = X[aa * (MM * DD) + d] - Y[aa * (MM * DD) + d];
        acc = fmaf(df * df, 1.0f / 4096.0f, acc);
    }
    #pragma unroll
    for (int off = 32; off > 0; off >>= 1) acc += __shfl_down(acc, off);
    if ((tid & 63) == 0) red[tid >> 6] = acc;
    __syncthreads();
    if (tid == 0) out[0] = red[0] + red[1] + red[2] + red[3];
}

extern "C" void kernel_launch(void* const* d_in, const int* in_sizes, int n_in,
                              void* d_out, int out_size, void* d_ws, size_t ws_size,
                              hipStream_t stream) {
    const float* X = (const float*)d_in[0];
    const float* Y = (const float*)d_in[1];
    float* out = (float*)d_out;
    int4*  frag = (int4*)d_ws;
    float* partials = (float*)((char*)d_ws + PART_OFF);

    hipLaunchKernelGGL(prep_frags, dim3(256), dim3(256), 0, stream, X, Y, frag);
    hipLaunchKernelGGL(sig_pde, dim3(NBLK), dim3(256), 0, stream, frag, partials);
    hipLaunchKernelGGL(final_sum, dim3(1), dim3(256), 0, stream, X, Y, partials, out);
}